// Round 1
// baseline (428.836 us; speedup 1.0000x reference)
//
#include <hip/hip_runtime.h>
#include <hip/hip_bf16.h>

typedef __bf16 bf16;
typedef __bf16 bf16x4 __attribute__((ext_vector_type(4)));
typedef __bf16 bf16x8 __attribute__((ext_vector_type(8)));
typedef float f32x4 __attribute__((ext_vector_type(4)));

#define B_ 32
#define S_ 512
#define D_ 1024
#define H_ 16
#define DH_ 64
#define M_ (B_*S_)   // 16384

__device__ __forceinline__ void async16(const void* g, void* l) {
  __builtin_amdgcn_global_load_lds(
      (const __attribute__((address_space(1))) unsigned int*)g,
      (__attribute__((address_space(3))) unsigned int*)l, 16, 0, 0);
}

__device__ __forceinline__ bf16x8 ld8u(const bf16* p) { // 8B-aligned 8x bf16
  bf16x4 a = *(const bf16x4*)p;
  bf16x4 b = *(const bf16x4*)(p + 4);
  bf16x8 r;
  r[0]=a[0]; r[1]=a[1]; r[2]=a[2]; r[3]=a[3];
  r[4]=b[0]; r[5]=b[1]; r[6]=b[2]; r[7]=b[3];
  return r;
}

// ---------------- LayerNorm + bf16 cast (both tensors in one launch) ----------
__global__ __launch_bounds__(256) void ln_bf16(
    const float* __restrict__ qk, const float* __restrict__ v,
    const float* __restrict__ g1, const float* __restrict__ b1,
    const float* __restrict__ g2, const float* __restrict__ b2,
    bf16* __restrict__ o1, bf16* __restrict__ o2)
{
  int row = blockIdx.x;
  const float* src; const float* g; const float* b; bf16* o; int r;
  if (row < M_) { src=qk; g=g1; b=b1; o=o1; r=row; }
  else          { src=v;  g=g2; b=b2; o=o2; r=row-M_; }
  int t = threadIdx.x;
  float4 x = ((const float4*)(src + (size_t)r*D_))[t];
  float s  = x.x+x.y+x.z+x.w;
  float ss = x.x*x.x + x.y*x.y + x.z*x.z + x.w*x.w;
  #pragma unroll
  for (int off=32; off>=1; off>>=1) {
    s  += __shfl_xor(s,  off, 64);
    ss += __shfl_xor(ss, off, 64);
  }
  __shared__ float red[8];
  int w = t>>6, l = t&63;
  if (l==0){ red[w]=s; red[4+w]=ss; }
  __syncthreads();
  s  = red[0]+red[1]+red[2]+red[3];
  ss = red[4]+red[5]+red[6]+red[7];
  float mu  = s*(1.f/D_);
  float var = ss*(1.f/D_) - mu*mu;
  float rs  = rsqrtf(var + 1e-5f);
  float4 gg = ((const float4*)g)[t];
  float4 bb = ((const float4*)b)[t];
  bf16x4 ov;
  ov[0] = (bf16)((x.x-mu)*rs*gg.x + bb.x);
  ov[1] = (bf16)((x.y-mu)*rs*gg.y + bb.y);
  ov[2] = (bf16)((x.z-mu)*rs*gg.z + bb.z);
  ov[3] = (bf16)((x.w-mu)*rs*gg.w + bb.w);
  ((bf16x4*)(o + (size_t)r*D_))[t] = ov;
}

// ---------------- Weight transpose + bf16 cast: Wt[N][K] = W[K][N] ------------
__global__ void wtrans(const float* __restrict__ W0, const float* __restrict__ W1,
                       const float* __restrict__ W2, const float* __restrict__ W3,
                       bf16* __restrict__ o0, bf16* __restrict__ o1,
                       bf16* __restrict__ o2, bf16* __restrict__ o3)
{
  int z = blockIdx.z;
  const float* W = z==0?W0: z==1?W1: z==2?W2: W3;
  bf16* o        = z==0?o0: z==1?o1: z==2?o2: o3;
  __shared__ float tile[32][33];
  int n0 = blockIdx.x*32, k0 = blockIdx.y*32;
  int tx = threadIdx.x, ty = threadIdx.y;   // block (32,8)
  #pragma unroll
  for (int i=0;i<4;i++) tile[ty + i*8][tx] = W[(size_t)(k0+ty+i*8)*D_ + n0+tx];
  __syncthreads();
  #pragma unroll
  for (int i=0;i<4;i++) o[(size_t)(n0+ty+i*8)*D_ + k0+tx] = (bf16)tile[tx][ty+i*8];
}

// ---------------- GEMM: C[M,N] = A[M,K] * Bt[N,K]^T + bias (+res) -------------
// 128x128 tile, BK=32, 256 threads = 4 waves (2x2), each wave 64x64 out.
template<int DO_RES>
__global__ __launch_bounds__(256) void gemm_bt(
    const bf16* __restrict__ A, const bf16* __restrict__ Bt,
    const float* __restrict__ bias, const bf16* __restrict__ res,
    bf16* __restrict__ outb, float* __restrict__ outf)
{
  __shared__ bf16 A_sh[128*32];
  __shared__ bf16 B_sh[128*32];
  int t = threadIdx.x;
  int n0 = blockIdx.x*128, m0 = blockIdx.y*128;
  int w = t>>6, l = t&63, lr = l&15, lg = l>>4;
  int wm = w>>1, wn = w&1;
  f32x4 acc[4][4];
  #pragma unroll
  for (int m=0;m<4;m++)
    #pragma unroll
    for (int n=0;n<4;n++) acc[m][n] = (f32x4){0.f,0.f,0.f,0.f};

  for (int kt=0; kt<32; ++kt) {
    const bf16* Ab = A  + (size_t)m0*D_ + kt*32;
    const bf16* Bb = Bt + (size_t)n0*D_ + kt*32;
    #pragma unroll
    for (int i=0;i<2;i++){
      int g = t + i*256;
      int row = g>>2, cc = g&3;
      async16(Ab + (size_t)row*D_ + cc*8, &A_sh[g*8]);
      async16(Bb + (size_t)row*D_ + cc*8, &B_sh[g*8]);
    }
    __syncthreads();
    bf16x8 af[4], bfr[4];
    #pragma unroll
    for (int m=0;m<4;m++) af[m]  = *(const bf16x8*)&A_sh[(wm*64 + m*16 + lr)*32 + lg*8];
    #pragma unroll
    for (int n=0;n<4;n++) bfr[n] = *(const bf16x8*)&B_sh[(wn*64 + n*16 + lr)*32 + lg*8];
    #pragma unroll
    for (int m=0;m<4;m++)
      #pragma unroll
      for (int n=0;n<4;n++)
        acc[m][n] = __builtin_amdgcn_mfma_f32_16x16x32_bf16(af[m], bfr[n], acc[m][n], 0,0,0);
    __syncthreads();
  }
  #pragma unroll
  for (int m=0;m<4;m++){
    #pragma unroll
    for (int j=0;j<4;j++){
      size_t row = (size_t)m0 + wm*64 + m*16 + lg*4 + j;
      #pragma unroll
      for (int n=0;n<4;n++){
        int col = n0 + wn*64 + n*16 + lr;
        float val = acc[m][n][j] + bias[col];
        size_t idx = row*D_ + col;
        if (DO_RES) outf[idx] = val + (float)res[idx];
        else        outb[idx] = (bf16)val;
      }
    }
  }
}

// ---------------- Flash attention: 1 block = (b, h, 64 q-rows) ----------------
__global__ __launch_bounds__(256) void attn_fwd(
    const bf16* __restrict__ Q, const bf16* __restrict__ K,
    const bf16* __restrict__ V, const int* __restrict__ mask,
    bf16* __restrict__ ctx)
{
  int b = blockIdx.z, h = blockIdx.y, q0 = blockIdx.x*64;
  int t = threadIdx.x, w = t>>6, l = t&63, lr = l&15, lg = l>>4;
  __shared__ bf16 Q_sh[64*68], K_sh[64*68], V_sh[64*68], P_sh[64*68];
  __shared__ float msk[512];
  for (int i=t;i<512;i+=256) msk[i] = mask[b*S_+i] ? 0.f : -1e9f;
  size_t base = ((size_t)(b*S_ + q0)*H_ + h)*DH_;
  {
    int qr = t>>2, cc = t&3;
    const bf16* src = Q + base + (size_t)qr*D_ + cc*16;
    bf16* dst = &Q_sh[qr*68 + cc*16];
    #pragma unroll
    for (int i=0;i<4;i++) ((bf16x4*)dst)[i] = ((const bf16x4*)src)[i];
  }
  __syncthreads();
  bf16x8 qa[2];
  #pragma unroll
  for (int kk=0;kk<2;kk++) qa[kk] = ld8u(&Q_sh[(w*16+lr)*68 + kk*32 + lg*8]);

  f32x4 cacc[4];
  #pragma unroll
  for (int n=0;n<4;n++) cacc[n] = (f32x4){0.f,0.f,0.f,0.f};
  float mrun[4], lrun[4];
  #pragma unroll
  for (int j=0;j<4;j++){ mrun[j] = -3.0e38f; lrun[j] = 0.f; }

  for (int kt=0; kt<8; ++kt) {
    size_t kb = ((size_t)(b*S_ + kt*64)*H_ + h)*DH_;
    {
      int qr = t>>2, cc = t&3;
      const bf16* ks = K + kb + (size_t)qr*D_ + cc*16;
      const bf16* vs = V + kb + (size_t)qr*D_ + cc*16;
      bf16* kd = &K_sh[qr*68 + cc*16];
      bf16* vd = &V_sh[qr*68 + cc*16];
      #pragma unroll
      for (int i=0;i<4;i++) ((bf16x4*)kd)[i] = ((const bf16x4*)ks)[i];
      #pragma unroll
      for (int i=0;i<4;i++) ((bf16x4*)vd)[i] = ((const bf16x4*)vs)[i];
    }
    __syncthreads();

    // S = Q K^T  (per wave: q rows w*16..+16, all 64 keys of the tile)
    float p[4][4];
    #pragma unroll
    for (int n=0;n<4;n++){
      f32x4 sa = (f32x4){0.f,0.f,0.f,0.f};
      #pragma unroll
      for (int kk=0;kk<2;kk++){
        bf16x8 kbf = ld8u(&K_sh[(n*16+lr)*68 + kk*32 + lg*8]);
        sa = __builtin_amdgcn_mfma_f32_16x16x32_bf16(qa[kk], kbf, sa, 0,0,0);
      }
      float madd = msk[kt*64 + n*16 + lr];
      #pragma unroll
      for (int j=0;j<4;j++) p[n][j] = sa[j]*0.125f + madd;
    }

    // online softmax (row stats live in the 16-lane column group)
    #pragma unroll
    for (int j=0;j<4;j++){
      float pm = fmaxf(fmaxf(p[0][j],p[1][j]), fmaxf(p[2][j],p[3][j]));
      #pragma unroll
      for (int off=1; off<16; off<<=1) pm = fmaxf(pm, __shfl_xor(pm, off, 64));
      float mnew = fmaxf(mrun[j], pm);
      float alpha = __expf(mrun[j] - mnew);
      mrun[j] = mnew;
      float ps = 0.f;
      #pragma unroll
      for (int n=0;n<4;n++){ p[n][j] = __expf(p[n][j] - mnew); ps += p[n][j]; }
      #pragma unroll
      for (int off=1; off<16; off<<=1) ps += __shfl_xor(ps, off, 64);
      lrun[j] = lrun[j]*alpha + ps;
      #pragma unroll
      for (int n=0;n<4;n++) cacc[n][j] *= alpha;
    }

    // P -> LDS (wave-private rows, D-layout -> A-layout re-distribution)
    #pragma unroll
    for (int n=0;n<4;n++)
      #pragma unroll
      for (int j=0;j<4;j++)
        P_sh[(w*16 + lg*4 + j)*68 + n*16 + lr] = (bf16)p[n][j];

    // ctx += P * V
    #pragma unroll
    for (int nd=0;nd<4;nd++){
      #pragma unroll
      for (int kk=0;kk<2;kk++){
        bf16x8 pa = ld8u(&P_sh[(w*16+lr)*68 + kk*32 + lg*8]);
        bf16x8 vb;
        #pragma unroll
        for (int r=0;r<8;r++) vb[r] = V_sh[(kk*32 + lg*8 + r)*68 + nd*16 + lr];
        cacc[nd] = __builtin_amdgcn_mfma_f32_16x16x32_bf16(pa, vb, cacc[nd], 0,0,0);
      }
    }
    __syncthreads();
  }
  #pragma unroll
  for (int nd=0;nd<4;nd++)
    #pragma unroll
    for (int j=0;j<4;j++){
      float val = cacc[nd][j] / lrun[j];
      ctx[base + (size_t)(w*16 + lg*4 + j)*D_ + nd*16 + lr] = (bf16)val;
    }
}

// ------------------------------ launcher --------------------------------------
extern "C" void kernel_launch(void* const* d_in, const int* in_sizes, int n_in,
                              void* d_out, int out_size, void* d_ws, size_t ws_size,
                              hipStream_t stream)
{
  (void)in_sizes; (void)n_in; (void)out_size; (void)ws_size;
  const float* qk   = (const float*)d_in[0];
  const float* v    = (const float*)d_in[1];
  const int*   mask = (const int*)  d_in[2];
  const float* qk_g = (const float*)d_in[3];
  const float* qk_b = (const float*)d_in[4];
  const float* v_g  = (const float*)d_in[5];
  const float* v_b  = (const float*)d_in[6];
  const float* Wq   = (const float*)d_in[7];
  const float* bq   = (const float*)d_in[8];
  const float* Wk   = (const float*)d_in[9];
  const float* bk   = (const float*)d_in[10];
  const float* Wv   = (const float*)d_in[11];
  const float* bv   = (const float*)d_in[12];
  const float* Wo   = (const float*)d_in[13];
  const float* bo   = (const float*)d_in[14];
  float* out = (float*)d_out;

  char* ws = (char*)d_ws;
  size_t off = 0;
  auto alloc = [&](size_t bytes){ void* p = ws + off; off += (bytes + 255) & ~(size_t)255; return p; };
  bf16* qkn = (bf16*)alloc((size_t)M_*D_*2);
  bf16* vn  = (bf16*)alloc((size_t)M_*D_*2);
  bf16* Qb  = (bf16*)alloc((size_t)M_*D_*2);
  bf16* Kb  = (bf16*)alloc((size_t)M_*D_*2);
  bf16* Vb  = (bf16*)alloc((size_t)M_*D_*2);
  bf16* Cb  = (bf16*)alloc((size_t)M_*D_*2);
  bf16* WqT = (bf16*)alloc((size_t)D_*D_*2);
  bf16* WkT = (bf16*)alloc((size_t)D_*D_*2);
  bf16* WvT = (bf16*)alloc((size_t)D_*D_*2);
  bf16* WoT = (bf16*)alloc((size_t)D_*D_*2);

  ln_bf16<<<2*M_, 256, 0, stream>>>(qk, v, qk_g, qk_b, v_g, v_b, qkn, vn);
  wtrans<<<dim3(32,32,4), dim3(32,8), 0, stream>>>(Wq, Wk, Wv, Wo, WqT, WkT, WvT, WoT);
  dim3 gg(D_/128, M_/128);
  gemm_bt<0><<<gg, 256, 0, stream>>>(qkn, WqT, bq, nullptr, Qb, nullptr);
  gemm_bt<0><<<gg, 256, 0, stream>>>(qkn, WkT, bk, nullptr, Kb, nullptr);
  gemm_bt<0><<<gg, 256, 0, stream>>>(vn,  WvT, bv, nullptr, Vb, nullptr);
  attn_fwd<<<dim3(S_/64, H_, B_), 256, 0, stream>>>(Qb, Kb, Vb, mask, Cb);
  gemm_bt<1><<<gg, 256, 0, stream>>>(Cb, WoT, bo, vn, nullptr, out);
}

// Round 2
// 362.050 us; speedup vs baseline: 1.1845x; 1.1845x over previous
//
#include <hip/hip_runtime.h>
#include <hip/hip_bf16.h>

typedef __bf16 bf16;
typedef __bf16 bf16x4 __attribute__((ext_vector_type(4)));
typedef __bf16 bf16x8 __attribute__((ext_vector_type(8)));
typedef float f32x4 __attribute__((ext_vector_type(4)));

#define B_ 32
#define S_ 512
#define D_ 1024
#define H_ 16
#define DH_ 64
#define M_ (B_*S_)   // 16384

__device__ __forceinline__ void async16(const void* g, void* l) {
  __builtin_amdgcn_global_load_lds(
      (const __attribute__((address_space(1))) unsigned int*)g,
      (__attribute__((address_space(3))) unsigned int*)l, 16, 0, 0);
}

// ---------------- LayerNorm + bf16 cast (both tensors in one launch) ----------
__global__ __launch_bounds__(256) void ln_bf16(
    const float* __restrict__ qk, const float* __restrict__ v,
    const float* __restrict__ g1, const float* __restrict__ b1,
    const float* __restrict__ g2, const float* __restrict__ b2,
    bf16* __restrict__ o1, bf16* __restrict__ o2)
{
  int row = blockIdx.x;
  const float* src; const float* g; const float* b; bf16* o; int r;
  if (row < M_) { src=qk; g=g1; b=b1; o=o1; r=row; }
  else          { src=v;  g=g2; b=b2; o=o2; r=row-M_; }
  int t = threadIdx.x;
  float4 x = ((const float4*)(src + (size_t)r*D_))[t];
  float s  = x.x+x.y+x.z+x.w;
  float ss = x.x*x.x + x.y*x.y + x.z*x.z + x.w*x.w;
  #pragma unroll
  for (int off=32; off>=1; off>>=1) {
    s  += __shfl_xor(s,  off, 64);
    ss += __shfl_xor(ss, off, 64);
  }
  __shared__ float red[8];
  int w = t>>6, l = t&63;
  if (l==0){ red[w]=s; red[4+w]=ss; }
  __syncthreads();
  s  = red[0]+red[1]+red[2]+red[3];
  ss = red[4]+red[5]+red[6]+red[7];
  float mu  = s*(1.f/D_);
  float var = ss*(1.f/D_) - mu*mu;
  float rs  = rsqrtf(var + 1e-5f);
  float4 gg = ((const float4*)g)[t];
  float4 bb = ((const float4*)b)[t];
  bf16x4 ov;
  ov[0] = (bf16)((x.x-mu)*rs*gg.x + bb.x);
  ov[1] = (bf16)((x.y-mu)*rs*gg.y + bb.y);
  ov[2] = (bf16)((x.z-mu)*rs*gg.z + bb.z);
  ov[3] = (bf16)((x.w-mu)*rs*gg.w + bb.w);
  ((bf16x4*)(o + (size_t)r*D_))[t] = ov;
}

// ---------------- Weight transpose + bf16 cast: Wt[N][K] = W[K][N] ------------
__global__ void wtrans(const float* __restrict__ W0, const float* __restrict__ W1,
                       const float* __restrict__ W2, const float* __restrict__ W3,
                       bf16* __restrict__ o0, bf16* __restrict__ o1,
                       bf16* __restrict__ o2, bf16* __restrict__ o3)
{
  int z = blockIdx.z;
  const float* W = z==0?W0: z==1?W1: z==2?W2: W3;
  bf16* o        = z==0?o0: z==1?o1: z==2?o2: o3;
  __shared__ float tile[32][33];
  int n0 = blockIdx.x*32, k0 = blockIdx.y*32;
  int tx = threadIdx.x, ty = threadIdx.y;   // block (32,8)
  #pragma unroll
  for (int i=0;i<4;i++) tile[ty + i*8][tx] = W[(size_t)(k0+ty+i*8)*D_ + n0+tx];
  __syncthreads();
  #pragma unroll
  for (int i=0;i<4;i++) o[(size_t)(n0+ty+i*8)*D_ + k0+tx] = (bf16)tile[tx][ty+i*8];
}

// ---------------- GEMM: C[M,N] = A[M,K] * Bt[N,K]^T + bias -------------------
// 128x128 tile, BK=32, 256 threads = 4 waves (2x2).
// MODE 0: N=2048, split outputs (Q | K), bf16 row-major
// MODE 1: N=1024, V^T layout out: [b][h][dh][s]
// MODE 2: N=1024, f32 out + residual
template<int MODE>
__global__ __launch_bounds__(256) void gemm_bt(
    const bf16* __restrict__ A, const bf16* __restrict__ Bt,
    const float* __restrict__ bias0, const float* __restrict__ bias1,
    const bf16* __restrict__ res,
    bf16* __restrict__ out0, bf16* __restrict__ out1, float* __restrict__ outf)
{
  __shared__ bf16 A_sh[128*32];
  __shared__ bf16 B_sh[128*32];
  int t = threadIdx.x;
  // bijective XCD-chunk swizzle (8 XCDs; nwg divisible by 8 here)
  int nwg  = gridDim.x * gridDim.y;
  int orig = blockIdx.y * gridDim.x + blockIdx.x;
  int qch  = nwg >> 3;
  int wg   = (orig & 7) * qch + (orig >> 3);
  int bx = wg % gridDim.x, by = wg / gridDim.x;
  int n0 = bx*128, m0 = by*128;
  int w = t>>6, l = t&63, lr = l&15, lg = l>>4;
  int wm = w>>1, wn = w&1;
  f32x4 acc[4][4];
  #pragma unroll
  for (int m=0;m<4;m++)
    #pragma unroll
    for (int n=0;n<4;n++) acc[m][n] = (f32x4){0.f,0.f,0.f,0.f};

  for (int kt=0; kt<32; ++kt) {
    const bf16* Ab = A  + (size_t)m0*D_ + kt*32;
    const bf16* Bb = Bt + (size_t)n0*D_ + kt*32;
    #pragma unroll
    for (int i=0;i<2;i++){
      int g = t + i*256;
      int row = g>>2, cc = g&3;
      async16(Ab + (size_t)row*D_ + cc*8, &A_sh[g*8]);
      async16(Bb + (size_t)row*D_ + cc*8, &B_sh[g*8]);
    }
    __syncthreads();
    bf16x8 af[4], bfr[4];
    #pragma unroll
    for (int m=0;m<4;m++) af[m]  = *(const bf16x8*)&A_sh[(wm*64 + m*16 + lr)*32 + lg*8];
    #pragma unroll
    for (int n=0;n<4;n++) bfr[n] = *(const bf16x8*)&B_sh[(wn*64 + n*16 + lr)*32 + lg*8];
    #pragma unroll
    for (int m=0;m<4;m++)
      #pragma unroll
      for (int n=0;n<4;n++)
        acc[m][n] = __builtin_amdgcn_mfma_f32_16x16x32_bf16(af[m], bfr[n], acc[m][n], 0,0,0);
    __syncthreads();
  }

  if (MODE == 0) {
    #pragma unroll
    for (int n=0;n<4;n++){
      int col = n0 + wn*64 + n*16 + lr;
      bf16* dst; int c;
      if (col < D_) { dst = out0; c = col; } else { dst = out1; c = col - D_; }
      float bv = (col < D_) ? bias0[c] : bias1[c];
      #pragma unroll
      for (int m=0;m<4;m++){
        #pragma unroll
        for (int j=0;j<4;j++){
          size_t row = (size_t)m0 + wm*64 + m*16 + lg*4 + j;
          dst[row*D_ + c] = (bf16)(acc[m][n][j] + bv);
        }
      }
    }
  } else if (MODE == 1) {
    // out0 is VT: [b][h][dh][s] ; row = b*512+s ; col = h*64+dh
    #pragma unroll
    for (int n=0;n<4;n++){
      int col = n0 + wn*64 + n*16 + lr;
      int h = col >> 6, dh = col & 63;
      float bv = bias0[col];
      #pragma unroll
      for (int m=0;m<4;m++){
        int row = m0 + wm*64 + m*16 + lg*4;    // j=0 base; 4 consecutive s
        int b = row >> 9, s = row & 511;
        bf16x4 pk;
        #pragma unroll
        for (int j=0;j<4;j++) pk[j] = (bf16)(acc[m][n][j] + bv);
        *(bf16x4*)&out0[((size_t)(b*H_ + h)*DH_ + dh)*S_ + s] = pk;
      }
    }
  } else {
    #pragma unroll
    for (int m=0;m<4;m++){
      #pragma unroll
      for (int j=0;j<4;j++){
        size_t row = (size_t)m0 + wm*64 + m*16 + lg*4 + j;
        #pragma unroll
        for (int n=0;n<4;n++){
          int col = n0 + wn*64 + n*16 + lr;
          size_t idx = row*D_ + col;
          outf[idx] = acc[m][n][j] + bias0[col] + (float)res[idx];
        }
      }
    }
  }
}

// ---------------- Flash attention: 1 block = (b, h, 64 q-rows) ----------------
// K: [b][s][h][dh] row-major (stride D_); VT: [b][h][dh][s]
__global__ __launch_bounds__(256) void attn_fwd(
    const bf16* __restrict__ Q, const bf16* __restrict__ K,
    const bf16* __restrict__ VT, const int* __restrict__ mask,
    bf16* __restrict__ ctx)
{
  int b = blockIdx.z, h = blockIdx.y, q0 = blockIdx.x*64;
  int t = threadIdx.x, w = t>>6, l = t&63, lr = l&15, lg = l>>4;
  __shared__ bf16 Q_sh[64*72], K_sh[64*72], VT_sh[64*72], P_sh[64*72];
  __shared__ float msk[512];
  const float SC = 0.125f * 1.44269504f;     // 1/sqrt(64) * log2(e)
  for (int i=t;i<512;i+=256) msk[i] = mask[b*S_+i] ? 0.f : -1.44269504e9f;
  size_t base = ((size_t)(b*S_ + q0)*H_ + h)*DH_;
  {
    int qr = t>>2, cc = (t&3)*16;
    const uint4* src = (const uint4*)(Q + base + (size_t)qr*D_ + cc);
    uint4 a0 = src[0], a1 = src[1];
    *(uint4*)&Q_sh[qr*72 + cc]     = a0;
    *(uint4*)&Q_sh[qr*72 + cc + 8] = a1;
  }
  __syncthreads();
  bf16x8 qa[2];
  #pragma unroll
  for (int kk=0;kk<2;kk++) qa[kk] = *(const bf16x8*)&Q_sh[(w*16+lr)*72 + kk*32 + lg*8];

  f32x4 cacc[4];
  #pragma unroll
  for (int n=0;n<4;n++) cacc[n] = (f32x4){0.f,0.f,0.f,0.f};
  float mrun[4], lrun[4];
  #pragma unroll
  for (int j=0;j<4;j++){ mrun[j] = -3.0e38f; lrun[j] = 0.f; }

  size_t vtbase = (size_t)(b*H_ + h)*DH_*S_;   // + dh*S_ + s
  for (int kt=0; kt<8; ++kt) {
    size_t kb = ((size_t)(b*S_ + kt*64)*H_ + h)*DH_;
    {
      int r = t>>2, cc = (t&3)*16;
      const uint4* ks = (const uint4*)(K + kb + (size_t)r*D_ + cc);
      const uint4* vs = (const uint4*)(VT + vtbase + (size_t)r*S_ + kt*64 + cc);
      uint4 k0 = ks[0], k1 = ks[1];
      uint4 v0 = vs[0], v1 = vs[1];
      *(uint4*)&K_sh[r*72 + cc]      = k0;
      *(uint4*)&K_sh[r*72 + cc + 8]  = k1;
      *(uint4*)&VT_sh[r*72 + cc]     = v0;
      *(uint4*)&VT_sh[r*72 + cc + 8] = v1;
    }
    __syncthreads();

    // S = Q K^T (per wave: q rows w*16..+16, 64 keys); scores in log2 domain
    float p[4][4];
    #pragma unroll
    for (int n=0;n<4;n++){
      f32x4 sa = (f32x4){0.f,0.f,0.f,0.f};
      #pragma unroll
      for (int kk=0;kk<2;kk++){
        bf16x8 kf = *(const bf16x8*)&K_sh[(n*16+lr)*72 + kk*32 + lg*8];
        sa = __builtin_amdgcn_mfma_f32_16x16x32_bf16(qa[kk], kf, sa, 0,0,0);
      }
      float madd = msk[kt*64 + n*16 + lr];
      #pragma unroll
      for (int j=0;j<4;j++) p[n][j] = sa[j]*SC + madd;
    }

    // online softmax (row stats across the 16-lane lr group)
    #pragma unroll
    for (int j=0;j<4;j++){
      float pm = fmaxf(fmaxf(p[0][j],p[1][j]), fmaxf(p[2][j],p[3][j]));
      #pragma unroll
      for (int off=1; off<16; off<<=1) pm = fmaxf(pm, __shfl_xor(pm, off, 64));
      float mnew = fmaxf(mrun[j], pm);
      float alpha = exp2f(mrun[j] - mnew);
      mrun[j] = mnew;
      float ps = 0.f;
      #pragma unroll
      for (int n=0;n<4;n++){ p[n][j] = exp2f(p[n][j] - mnew); ps += p[n][j]; }
      #pragma unroll
      for (int off=1; off<16; off<<=1) ps += __shfl_xor(ps, off, 64);
      lrun[j] = lrun[j]*alpha + ps;
      #pragma unroll
      for (int n=0;n<4;n++) cacc[n][j] *= alpha;
    }

    // P -> LDS (wave-private rows), then A-fragments
    #pragma unroll
    for (int n=0;n<4;n++)
      #pragma unroll
      for (int j=0;j<4;j++)
        P_sh[(w*16 + lg*4 + j)*72 + n*16 + lr] = (bf16)p[n][j];

    bf16x8 pa[2];
    #pragma unroll
    for (int kk=0;kk<2;kk++) pa[kk] = *(const bf16x8*)&P_sh[(w*16+lr)*72 + kk*32 + lg*8];

    // ctx += P * V  (B-fragment = contiguous VT rows)
    #pragma unroll
    for (int nd=0;nd<4;nd++){
      #pragma unroll
      for (int kk=0;kk<2;kk++){
        bf16x8 vb = *(const bf16x8*)&VT_sh[(nd*16+lr)*72 + kk*32 + lg*8];
        cacc[nd] = __builtin_amdgcn_mfma_f32_16x16x32_bf16(pa[kk], vb, cacc[nd], 0,0,0);
      }
    }
    __syncthreads();
  }
  #pragma unroll
  for (int j=0;j<4;j++){
    float rl = 1.0f / lrun[j];
    #pragma unroll
    for (int nd=0;nd<4;nd++)
      ctx[base + (size_t)(w*16 + lg*4 + j)*D_ + nd*16 + lr] = (bf16)(cacc[nd][j] * rl);
  }
}

// ------------------------------ launcher --------------------------------------
extern "C" void kernel_launch(void* const* d_in, const int* in_sizes, int n_in,
                              void* d_out, int out_size, void* d_ws, size_t ws_size,
                              hipStream_t stream)
{
  (void)in_sizes; (void)n_in; (void)out_size; (void)ws_size;
  const float* qk   = (const float*)d_in[0];
  const float* v    = (const float*)d_in[1];
  const int*   mask = (const int*)  d_in[2];
  const float* qk_g = (const float*)d_in[3];
  const float* qk_b = (const float*)d_in[4];
  const float* v_g  = (const float*)d_in[5];
  const float* v_b  = (const float*)d_in[6];
  const float* Wq   = (const float*)d_in[7];
  const float* bq   = (const float*)d_in[8];
  const float* Wk   = (const float*)d_in[9];
  const float* bk   = (const float*)d_in[10];
  const float* Wv   = (const float*)d_in[11];
  const float* bv   = (const float*)d_in[12];
  const float* Wo   = (const float*)d_in[13];
  const float* bo   = (const float*)d_in[14];
  float* out = (float*)d_out;

  char* ws = (char*)d_ws;
  size_t off = 0;
  auto alloc = [&](size_t bytes){ void* p = ws + off; off += (bytes + 255) & ~(size_t)255; return p; };
  bf16* qkn  = (bf16*)alloc((size_t)M_*D_*2);
  bf16* vn   = (bf16*)alloc((size_t)M_*D_*2);
  bf16* Qb   = (bf16*)alloc((size_t)M_*D_*2);
  bf16* Kb   = (bf16*)alloc((size_t)M_*D_*2);
  bf16* VTb  = (bf16*)alloc((size_t)M_*D_*2);
  bf16* Cb   = (bf16*)alloc((size_t)M_*D_*2);
  bf16* WqkT = (bf16*)alloc((size_t)2*D_*D_*2);
  bf16* WvT  = (bf16*)alloc((size_t)D_*D_*2);
  bf16* WoT  = (bf16*)alloc((size_t)D_*D_*2);

  ln_bf16<<<2*M_, 256, 0, stream>>>(qk, v, qk_g, qk_b, v_g, v_b, qkn, vn);
  wtrans<<<dim3(32,32,4), dim3(32,8), 0, stream>>>(Wq, Wk, Wv, Wo,
      WqkT, WqkT + (size_t)D_*D_, WvT, WoT);
  gemm_bt<0><<<dim3(16,128), 256, 0, stream>>>(qkn, WqkT, bq, bk, nullptr, Qb, Kb, nullptr);
  gemm_bt<1><<<dim3(8,128),  256, 0, stream>>>(vn,  WvT,  bv, nullptr, nullptr, VTb, nullptr, nullptr);
  attn_fwd<<<dim3(S_/64, H_, B_), 256, 0, stream>>>(Qb, Kb, VTb, mask, Cb);
  gemm_bt<2><<<dim3(8,128),  256, 0, stream>>>(Cb, WoT, bo, nullptr, vn, nullptr, nullptr, out);
}

// Round 3
// 325.987 us; speedup vs baseline: 1.3155x; 1.1106x over previous
//
#include <hip/hip_runtime.h>
#include <hip/hip_bf16.h>

typedef __bf16 bf16;
typedef __bf16 bf16x2 __attribute__((ext_vector_type(2)));
typedef __bf16 bf16x4 __attribute__((ext_vector_type(4)));
typedef __bf16 bf16x8 __attribute__((ext_vector_type(8)));
typedef float f32x4 __attribute__((ext_vector_type(4)));

#define B_ 32
#define S_ 512
#define D_ 1024
#define H_ 16
#define DH_ 64
#define M_ (B_*S_)   // 16384

__device__ __forceinline__ void async16(const void* g, void* l) {
  __builtin_amdgcn_global_load_lds(
      (const __attribute__((address_space(1))) unsigned int*)g,
      (__attribute__((address_space(3))) unsigned int*)l, 16, 0, 0);
}

// ---------------- LayerNorm + bf16 cast (both tensors in one launch) ----------
__global__ __launch_bounds__(256) void ln_bf16(
    const float* __restrict__ qk, const float* __restrict__ v,
    const float* __restrict__ g1, const float* __restrict__ b1,
    const float* __restrict__ g2, const float* __restrict__ b2,
    bf16* __restrict__ o1, bf16* __restrict__ o2)
{
  int row = blockIdx.x;
  const float* src; const float* g; const float* b; bf16* o; int r;
  if (row < M_) { src=qk; g=g1; b=b1; o=o1; r=row; }
  else          { src=v;  g=g2; b=b2; o=o2; r=row-M_; }
  int t = threadIdx.x;
  float4 x = ((const float4*)(src + (size_t)r*D_))[t];
  float s  = x.x+x.y+x.z+x.w;
  float ss = x.x*x.x + x.y*x.y + x.z*x.z + x.w*x.w;
  #pragma unroll
  for (int off=32; off>=1; off>>=1) {
    s  += __shfl_xor(s,  off, 64);
    ss += __shfl_xor(ss, off, 64);
  }
  __shared__ float red[8];
  int w = t>>6, l = t&63;
  if (l==0){ red[w]=s; red[4+w]=ss; }
  __syncthreads();
  s  = red[0]+red[1]+red[2]+red[3];
  ss = red[4]+red[5]+red[6]+red[7];
  float mu  = s*(1.f/D_);
  float var = ss*(1.f/D_) - mu*mu;
  float rs  = rsqrtf(var + 1e-5f);
  float4 gg = ((const float4*)g)[t];
  float4 bb = ((const float4*)b)[t];
  bf16x4 ov;
  ov[0] = (bf16)((x.x-mu)*rs*gg.x + bb.x);
  ov[1] = (bf16)((x.y-mu)*rs*gg.y + bb.y);
  ov[2] = (bf16)((x.z-mu)*rs*gg.z + bb.z);
  ov[3] = (bf16)((x.w-mu)*rs*gg.w + bb.w);
  ((bf16x4*)(o + (size_t)r*D_))[t] = ov;
}

// ---------------- Weight transpose + bf16 cast: Wt[N][K] = W[K][N] ------------
__global__ void wtrans(const float* __restrict__ W0, const float* __restrict__ W1,
                       const float* __restrict__ W2, const float* __restrict__ W3,
                       bf16* __restrict__ o0, bf16* __restrict__ o1,
                       bf16* __restrict__ o2, bf16* __restrict__ o3)
{
  int z = blockIdx.z;
  const float* W = z==0?W0: z==1?W1: z==2?W2: W3;
  bf16* o        = z==0?o0: z==1?o1: z==2?o2: o3;
  __shared__ float tile[32][33];
  int n0 = blockIdx.x*32, k0 = blockIdx.y*32;
  int tx = threadIdx.x, ty = threadIdx.y;   // block (32,8)
  #pragma unroll
  for (int i=0;i<4;i++) tile[ty + i*8][tx] = W[(size_t)(k0+ty+i*8)*D_ + n0+tx];
  __syncthreads();
  #pragma unroll
  for (int i=0;i<4;i++) o[(size_t)(n0+ty+i*8)*D_ + k0+tx] = (bf16)tile[tx][ty+i*8];
}

// ---------------- GEMM: C[M,N] = A[M,K] * Bt[N,K]^T + bias -------------------
// 128x128 tile, BK=64, 256 threads = 4 waves (2x2). XOR-swizzled LDS (slot^row&7)
// via pre-swizzled global source + swizzled b128 reads (conflict-free).
template<int MODE>
__global__ __launch_bounds__(256) void gemm_bt(
    const bf16* __restrict__ A, const bf16* __restrict__ Bt,
    const float* __restrict__ bias0, const float* __restrict__ bias1,
    const bf16* __restrict__ res,
    bf16* __restrict__ out0, bf16* __restrict__ out1, float* __restrict__ outf)
{
  __shared__ bf16 A_sh[128*64];
  __shared__ bf16 B_sh[128*64];
  int t = threadIdx.x;
  int nwg  = gridDim.x * gridDim.y;
  int orig = blockIdx.y * gridDim.x + blockIdx.x;
  int qch  = nwg >> 3;
  int wg   = (orig & 7) * qch + (orig >> 3);
  int bx = wg % gridDim.x, by = wg / gridDim.x;
  int n0 = bx*128, m0 = by*128;
  int w = t>>6, l = t&63, lr = l&15, lg = (l>>4)&3;
  int wm = w>>1, wn = w&1;
  f32x4 acc[4][4];
  #pragma unroll
  for (int m=0;m<4;m++)
    #pragma unroll
    for (int n=0;n<4;n++) acc[m][n] = (f32x4){0.f,0.f,0.f,0.f};

  for (int kt=0; kt<16; ++kt) {
    const bf16* Ab = A  + (size_t)m0*D_ + kt*64;
    const bf16* Bb = Bt + (size_t)n0*D_ + kt*64;
    #pragma unroll
    for (int i=0;i<4;i++){
      int c = i*256 + t;
      int row = c>>3, slot = (c&7) ^ (row&7);
      async16(Ab + (size_t)row*D_ + slot*8, &A_sh[c*8]);
      async16(Bb + (size_t)row*D_ + slot*8, &B_sh[c*8]);
    }
    __syncthreads();
    bf16x8 af[4][2], bfr[4][2];
    #pragma unroll
    for (int m=0;m<4;m++){
      int row = wm*64 + m*16 + lr;
      #pragma unroll
      for (int kk=0;kk<2;kk++)
        af[m][kk] = *(const bf16x8*)&A_sh[row*64 + (((kk*4+lg)^(lr&7))*8)];
    }
    #pragma unroll
    for (int n=0;n<4;n++){
      int row = wn*64 + n*16 + lr;
      #pragma unroll
      for (int kk=0;kk<2;kk++)
        bfr[n][kk] = *(const bf16x8*)&B_sh[row*64 + (((kk*4+lg)^(lr&7))*8)];
    }
    #pragma unroll
    for (int kk=0;kk<2;kk++)
      #pragma unroll
      for (int m=0;m<4;m++)
        #pragma unroll
        for (int n=0;n<4;n++)
          acc[m][n] = __builtin_amdgcn_mfma_f32_16x16x32_bf16(af[m][kk], bfr[n][kk], acc[m][n], 0,0,0);
    __syncthreads();
  }

  if (MODE == 0) {
    #pragma unroll
    for (int n=0;n<4;n++){
      int col = n0 + wn*64 + n*16 + lr;
      bf16* dst; int c;
      if (col < D_) { dst = out0; c = col; } else { dst = out1; c = col - D_; }
      float bv = (col < D_) ? bias0[c] : bias1[c];
      #pragma unroll
      for (int m=0;m<4;m++){
        #pragma unroll
        for (int j=0;j<4;j++){
          size_t row = (size_t)m0 + wm*64 + m*16 + lg*4 + j;
          dst[row*D_ + c] = (bf16)(acc[m][n][j] + bv);
        }
      }
    }
  } else if (MODE == 1) {
    #pragma unroll
    for (int n=0;n<4;n++){
      int col = n0 + wn*64 + n*16 + lr;
      int h = col >> 6, dh = col & 63;
      float bv = bias0[col];
      #pragma unroll
      for (int m=0;m<4;m++){
        int row = m0 + wm*64 + m*16 + lg*4;
        int b = row >> 9, s = row & 511;
        bf16x4 pk;
        #pragma unroll
        for (int j=0;j<4;j++) pk[j] = (bf16)(acc[m][n][j] + bv);
        *(bf16x4*)&out0[((size_t)(b*H_ + h)*DH_ + dh)*S_ + s] = pk;
      }
    }
  } else {
    #pragma unroll
    for (int m=0;m<4;m++){
      #pragma unroll
      for (int j=0;j<4;j++){
        size_t row = (size_t)m0 + wm*64 + m*16 + lg*4 + j;
        #pragma unroll
        for (int n=0;n<4;n++){
          int col = n0 + wn*64 + n*16 + lr;
          size_t idx = row*D_ + col;
          outf[idx] = acc[m][n][j] + bias0[col] + (float)res[idx];
        }
      }
    }
  }
}

// ---------------- Flash attention, swapped-MFMA, fragment-packed LDS ----------
// K: [b][s][h][dh]; VT: [b][h][dh][s]. 1 block = (b,h,64 q rows), 4 waves.
__global__ __launch_bounds__(256) void attn_fwd(
    const bf16* __restrict__ Q, const bf16* __restrict__ K,
    const bf16* __restrict__ VT, const int* __restrict__ mask,
    bf16* __restrict__ ctx)
{
  // XCD-locality swizzle: consecutive works (same b,h) -> same XCD
  int flat = blockIdx.x + (blockIdx.y<<3) + (blockIdx.z<<7);   // grid (8,16,32)
  int work = (flat & 7)*512 + (flat >> 3);
  int qt = work & 7, h = (work>>3) & 15, b = work >> 7;
  int q0 = qt*64;
  int t = threadIdx.x, w = t>>6, l = t&63, lr = l&15, lg = (l>>4)&3;

  __shared__ bf16 Q_sh[4096];               // fragment-packed, 8KB
  __shared__ bf16 K_s0[4096], K_s1[4096];   // dbuf K tiles
  __shared__ bf16 V_s0[4096], V_s1[4096];   // dbuf V tiles
  __shared__ float msk[512];

  const float SC = 0.125f * 1.44269504f;
  for (int i=t;i<512;i+=256) msk[i] = mask[b*S_+i] ? 0.f : -1.44269504e9f;

  size_t qbase  = ((size_t)(b*S_ + q0)*H_ + h)*DH_;
  size_t vtbase = (size_t)(b*H_ + h)*DH_*S_;

  // stage Q fragment-packed: chunk c=((cw*2+ckk)*4+clg)*16+clr
  #pragma unroll
  for (int i=0;i<2;i++){
    int c = i*256 + t;
    int clr = c&15, clg=(c>>4)&3, ckk=(c>>6)&1, cw=c>>7;
    async16(Q + qbase + (size_t)(cw*16+clr)*D_ + ckk*32 + clg*8, &Q_sh[c*8]);
  }
  // stage K/V tile 0
  {
    size_t kb = ((size_t)(b*S_)*H_ + h)*DH_;
    #pragma unroll
    for (int i=0;i<2;i++){
      int c = i*256 + t;
      int clr = c&15, clg=(c>>4)&3, ckk=(c>>6)&1, cn=c>>7;
      async16(K + kb + (size_t)(cn*16+clr)*D_ + ckk*32 + clg*8, &K_s0[c*8]);
      async16(VT + vtbase + (size_t)(cn*16+clr)*S_ + ckk*32 + clg*8, &V_s0[c*8]);
    }
  }
  __syncthreads();

  bf16x8 qa[2];
  #pragma unroll
  for (int kk=0;kk<2;kk++)
    qa[kk] = *(const bf16x8*)&Q_sh[(((w*2+kk)*4+lg)*16+lr)*8];

  f32x4 cacc[4];
  #pragma unroll
  for (int n=0;n<4;n++) cacc[n] = (f32x4){0.f,0.f,0.f,0.f};
  float mrun = -3.0e38f, lrun = 0.f;

  for (int kt=0; kt<8; ++kt) {
    const bf16* Ks = (kt&1) ? K_s1 : K_s0;
    const bf16* Vs = (kt&1) ? V_s1 : V_s0;
    // prefetch next tile into other buffer
    if (kt < 7) {
      bf16* Kd = (kt&1) ? K_s0 : K_s1;
      bf16* Vd = (kt&1) ? V_s0 : V_s1;
      size_t kb = ((size_t)(b*S_ + (kt+1)*64)*H_ + h)*DH_;
      size_t vb = vtbase + (kt+1)*64;
      #pragma unroll
      for (int i=0;i<2;i++){
        int c = i*256 + t;
        int clr = c&15, clg=(c>>4)&3, ckk=(c>>6)&1, cn=c>>7;
        async16(K + kb + (size_t)(cn*16+clr)*D_ + ckk*32 + clg*8, &Kd[c*8]);
        async16(VT + vb + (size_t)(cn*16+clr)*S_ + ckk*32 + clg*8, &Vd[c*8]);
      }
    }

    // S^T = mfma(K, Q): lane holds S^T[key=n*16+lg*4+j][q=w*16+lr]
    float p[4][4];
    #pragma unroll
    for (int n=0;n<4;n++){
      f32x4 sa = (f32x4){0.f,0.f,0.f,0.f};
      #pragma unroll
      for (int kk=0;kk<2;kk++){
        bf16x8 kf = *(const bf16x8*)&Ks[(((n*2+kk)*4+lg)*16+lr)*8];
        sa = __builtin_amdgcn_mfma_f32_16x16x32_bf16(kf, qa[kk], sa, 0,0,0);
      }
      float4 mk = *(const float4*)&msk[kt*64 + n*16 + lg*4];
      p[n][0] = sa[0]*SC + mk.x;
      p[n][1] = sa[1]*SC + mk.y;
      p[n][2] = sa[2]*SC + mk.z;
      p[n][3] = sa[3]*SC + mk.w;
    }

    // per-lane online softmax for q = w*16+lr (keys split across lg groups)
    float pm = p[0][0];
    #pragma unroll
    for (int n=0;n<4;n++)
      #pragma unroll
      for (int j=0;j<4;j++) pm = fmaxf(pm, p[n][j]);
    pm = fmaxf(pm, __shfl_xor(pm, 16, 64));
    pm = fmaxf(pm, __shfl_xor(pm, 32, 64));
    float mnew  = fmaxf(mrun, pm);
    float alpha = exp2f(mrun - mnew);
    mrun = mnew;
    float ps = 0.f;
    #pragma unroll
    for (int n=0;n<4;n++)
      #pragma unroll
      for (int j=0;j<4;j++){ p[n][j] = exp2f(p[n][j] - mnew); ps += p[n][j]; }
    ps += __shfl_xor(ps, 16, 64);
    ps += __shfl_xor(ps, 32, 64);
    lrun = lrun*alpha + ps;
    #pragma unroll
    for (int n=0;n<4;n++) cacc[n] *= alpha;

    // pack P -> bf16 pairs
    unsigned pk[4][2];
    #pragma unroll
    for (int n=0;n<4;n++)
      #pragma unroll
      for (int i=0;i<2;i++){
        union { bf16x2 v; unsigned u; } u2;
        u2.v[0] = (bf16)p[n][2*i];
        u2.v[1] = (bf16)p[n][2*i+1];
        pk[n][i] = u2.u;
      }

    // redistribute to PV fragment: pa[kk] elem e -> P[q=w*16+lr][key=kk*32+lg*8+e]
    int srcbase = (l&15) + ((l&16)<<1);      // lr + 32*(lg&1)
    union UPA { unsigned u[4]; bf16x8 v; };
    UPA pa0, pa1;
    #pragma unroll
    for (int w4=0; w4<4; ++w4){
      int src = srcbase + ((w4&2)<<3);       // +16*(w4>>1)
      unsigned lo0 = __shfl(pk[0][w4&1], src, 64);
      unsigned hi0 = __shfl(pk[1][w4&1], src, 64);
      unsigned lo1 = __shfl(pk[2][w4&1], src, 64);
      unsigned hi1 = __shfl(pk[3][w4&1], src, 64);
      pa0.u[w4] = (l&32) ? hi0 : lo0;
      pa1.u[w4] = (l&32) ? hi1 : lo1;
    }

    // ctx^T-style PV: mfma(V^T, P^T) -> lane holds ctx[q=w*16+lr][dh=nd*16+lg*4+j]
    #pragma unroll
    for (int nd=0;nd<4;nd++){
      bf16x8 vb0 = *(const bf16x8*)&Vs[(((nd*2+0)*4+lg)*16+lr)*8];
      bf16x8 vb1 = *(const bf16x8*)&Vs[(((nd*2+1)*4+lg)*16+lr)*8];
      cacc[nd] = __builtin_amdgcn_mfma_f32_16x16x32_bf16(vb0, pa0.v, cacc[nd], 0,0,0);
      cacc[nd] = __builtin_amdgcn_mfma_f32_16x16x32_bf16(vb1, pa1.v, cacc[nd], 0,0,0);
    }
    __syncthreads();
  }

  float rl = 1.0f / lrun;
  size_t obase = qbase + (size_t)(w*16 + lr)*D_;
  #pragma unroll
  for (int nd=0;nd<4;nd++){
    bf16x4 o4;
    #pragma unroll
    for (int j=0;j<4;j++) o4[j] = (bf16)(cacc[nd][j]*rl);
    *(bf16x4*)&ctx[obase + nd*16 + lg*4] = o4;
  }
}

// ------------------------------ launcher --------------------------------------
extern "C" void kernel_launch(void* const* d_in, const int* in_sizes, int n_in,
                              void* d_out, int out_size, void* d_ws, size_t ws_size,
                              hipStream_t stream)
{
  (void)in_sizes; (void)n_in; (void)out_size; (void)ws_size;
  const float* qk   = (const float*)d_in[0];
  const float* v    = (const float*)d_in[1];
  const int*   mask = (const int*)  d_in[2];
  const float* qk_g = (const float*)d_in[3];
  const float* qk_b = (const float*)d_in[4];
  const float* v_g  = (const float*)d_in[5];
  const float* v_b  = (const float*)d_in[6];
  const float* Wq   = (const float*)d_in[7];
  const float* bq   = (const float*)d_in[8];
  const float* Wk   = (const float*)d_in[9];
  const float* bk   = (const float*)d_in[10];
  const float* Wv   = (const float*)d_in[11];
  const float* bv   = (const float*)d_in[12];
  const float* Wo   = (const float*)d_in[13];
  const float* bo   = (const float*)d_in[14];
  float* out = (float*)d_out;

  char* ws = (char*)d_ws;
  size_t off = 0;
  auto alloc = [&](size_t bytes){ void* p = ws + off; off += (bytes + 255) & ~(size_t)255; return p; };
  bf16* qkn  = (bf16*)alloc((size_t)M_*D_*2);
  bf16* vn   = (bf16*)alloc((size_t)M_*D_*2);
  bf16* Qb   = (bf16*)alloc((size_t)M_*D_*2);
  bf16* Kb   = (bf16*)alloc((size_t)M_*D_*2);
  bf16* VTb  = (bf16*)alloc((size_t)M_*D_*2);
  bf16* Cb   = (bf16*)alloc((size_t)M_*D_*2);
  bf16* WqkT = (bf16*)alloc((size_t)2*D_*D_*2);
  bf16* WvT  = (bf16*)alloc((size_t)D_*D_*2);
  bf16* WoT  = (bf16*)alloc((size_t)D_*D_*2);

  ln_bf16<<<2*M_, 256, 0, stream>>>(qk, v, qk_g, qk_b, v_g, v_b, qkn, vn);
  wtrans<<<dim3(32,32,4), dim3(32,8), 0, stream>>>(Wq, Wk, Wv, Wo,
      WqkT, WqkT + (size_t)D_*D_, WvT, WoT);
  gemm_bt<0><<<dim3(16,128), 256, 0, stream>>>(qkn, WqkT, bq, bk, nullptr, Qb, Kb, nullptr);
  gemm_bt<1><<<dim3(8,128),  256, 0, stream>>>(vn,  WvT,  bv, nullptr, nullptr, VTb, nullptr, nullptr);
  attn_fwd<<<dim3(8, 16, 32), 256, 0, stream>>>(Qb, Kb, VTb, mask, Cb);
  gemm_bt<2><<<dim3(8,128),  256, 0, stream>>>(Cb, WoT, bo, nullptr, vn, nullptr, nullptr, out);
}

// Round 4
// 297.547 us; speedup vs baseline: 1.4412x; 1.0956x over previous
//
#include <hip/hip_runtime.h>
#include <hip/hip_bf16.h>

typedef __bf16 bf16;
typedef __bf16 bf16x2 __attribute__((ext_vector_type(2)));
typedef __bf16 bf16x4 __attribute__((ext_vector_type(4)));
typedef __bf16 bf16x8 __attribute__((ext_vector_type(8)));
typedef float f32x4 __attribute__((ext_vector_type(4)));

#define B_ 32
#define S_ 512
#define D_ 1024
#define H_ 16
#define DH_ 64
#define M_ (B_*S_)   // 16384

#if __has_builtin(__builtin_amdgcn_exp2f)
#define FEXP2 __builtin_amdgcn_exp2f
#else
#define FEXP2 exp2f
#endif

__device__ __forceinline__ void async16(const void* g, void* l) {
  __builtin_amdgcn_global_load_lds(
      (const __attribute__((address_space(1))) unsigned int*)g,
      (__attribute__((address_space(3))) unsigned int*)l, 16, 0, 0);
}

// ---------------- LayerNorm + bf16 cast (both tensors in one launch) ----------
__global__ __launch_bounds__(256) void ln_bf16(
    const float* __restrict__ qk, const float* __restrict__ v,
    const float* __restrict__ g1, const float* __restrict__ b1,
    const float* __restrict__ g2, const float* __restrict__ b2,
    bf16* __restrict__ o1, bf16* __restrict__ o2)
{
  int row = blockIdx.x;
  const float* src; const float* g; const float* b; bf16* o; int r;
  if (row < M_) { src=qk; g=g1; b=b1; o=o1; r=row; }
  else          { src=v;  g=g2; b=b2; o=o2; r=row-M_; }
  int t = threadIdx.x;
  float4 x = ((const float4*)(src + (size_t)r*D_))[t];
  float s  = x.x+x.y+x.z+x.w;
  float ss = x.x*x.x + x.y*x.y + x.z*x.z + x.w*x.w;
  #pragma unroll
  for (int off=32; off>=1; off>>=1) {
    s  += __shfl_xor(s,  off, 64);
    ss += __shfl_xor(ss, off, 64);
  }
  __shared__ float red[8];
  int w = t>>6, l = t&63;
  if (l==0){ red[w]=s; red[4+w]=ss; }
  __syncthreads();
  s  = red[0]+red[1]+red[2]+red[3];
  ss = red[4]+red[5]+red[6]+red[7];
  float mu  = s*(1.f/D_);
  float var = ss*(1.f/D_) - mu*mu;
  float rs  = rsqrtf(var + 1e-5f);
  float4 gg = ((const float4*)g)[t];
  float4 bb = ((const float4*)b)[t];
  bf16x4 ov;
  ov[0] = (bf16)((x.x-mu)*rs*gg.x + bb.x);
  ov[1] = (bf16)((x.y-mu)*rs*gg.y + bb.y);
  ov[2] = (bf16)((x.z-mu)*rs*gg.z + bb.z);
  ov[3] = (bf16)((x.w-mu)*rs*gg.w + bb.w);
  ((bf16x4*)(o + (size_t)r*D_))[t] = ov;
}

// ---------------- Weight transpose + bf16 cast: Wt[N][K] = W[K][N] ------------
__global__ void wtrans(const float* __restrict__ W0, const float* __restrict__ W1,
                       const float* __restrict__ W2, const float* __restrict__ W3,
                       bf16* __restrict__ o0, bf16* __restrict__ o1,
                       bf16* __restrict__ o2, bf16* __restrict__ o3)
{
  int z = blockIdx.z;
  const float* W = z==0?W0: z==1?W1: z==2?W2: W3;
  bf16* o        = z==0?o0: z==1?o1: z==2?o2: o3;
  __shared__ float tile[32][33];
  int n0 = blockIdx.x*32, k0 = blockIdx.y*32;
  int tx = threadIdx.x, ty = threadIdx.y;   // block (32,8)
  #pragma unroll
  for (int i=0;i<4;i++) tile[ty + i*8][tx] = W[(size_t)(k0+ty+i*8)*D_ + n0+tx];
  __syncthreads();
  #pragma unroll
  for (int i=0;i<4;i++) o[(size_t)(n0+ty+i*8)*D_ + k0+tx] = (bf16)tile[tx][ty+i*8];
}

// ---------------- GEMM: C[M,N] = A[M,K] * Bt[N,K]^T + bias -------------------
template<int MODE>
__global__ __launch_bounds__(256) void gemm_bt(
    const bf16* __restrict__ A, const bf16* __restrict__ Bt,
    const float* __restrict__ bias0, const float* __restrict__ bias1,
    const bf16* __restrict__ res,
    bf16* __restrict__ out0, bf16* __restrict__ out1, float* __restrict__ outf)
{
  __shared__ bf16 A_sh[128*64];
  __shared__ bf16 B_sh[128*64];
  int t = threadIdx.x;
  int nwg  = gridDim.x * gridDim.y;
  int orig = blockIdx.y * gridDim.x + blockIdx.x;
  int qch  = nwg >> 3;
  int wg   = (orig & 7) * qch + (orig >> 3);
  int bx = wg % gridDim.x, by = wg / gridDim.x;
  int n0 = bx*128, m0 = by*128;
  int w = t>>6, l = t&63, lr = l&15, lg = (l>>4)&3;
  int wm = w>>1, wn = w&1;
  f32x4 acc[4][4];
  #pragma unroll
  for (int m=0;m<4;m++)
    #pragma unroll
    for (int n=0;n<4;n++) acc[m][n] = (f32x4){0.f,0.f,0.f,0.f};

  for (int kt=0; kt<16; ++kt) {
    const bf16* Ab = A  + (size_t)m0*D_ + kt*64;
    const bf16* Bb = Bt + (size_t)n0*D_ + kt*64;
    #pragma unroll
    for (int i=0;i<4;i++){
      int c = i*256 + t;
      int row = c>>3, slot = (c&7) ^ (row&7);
      async16(Ab + (size_t)row*D_ + slot*8, &A_sh[c*8]);
      async16(Bb + (size_t)row*D_ + slot*8, &B_sh[c*8]);
    }
    __syncthreads();
    bf16x8 af[4][2], bfr[4][2];
    #pragma unroll
    for (int m=0;m<4;m++){
      int row = wm*64 + m*16 + lr;
      #pragma unroll
      for (int kk=0;kk<2;kk++)
        af[m][kk] = *(const bf16x8*)&A_sh[row*64 + (((kk*4+lg)^(lr&7))*8)];
    }
    #pragma unroll
    for (int n=0;n<4;n++){
      int row = wn*64 + n*16 + lr;
      #pragma unroll
      for (int kk=0;kk<2;kk++)
        bfr[n][kk] = *(const bf16x8*)&B_sh[row*64 + (((kk*4+lg)^(lr&7))*8)];
    }
    #pragma unroll
    for (int kk=0;kk<2;kk++)
      #pragma unroll
      for (int m=0;m<4;m++)
        #pragma unroll
        for (int n=0;n<4;n++)
          acc[m][n] = __builtin_amdgcn_mfma_f32_16x16x32_bf16(af[m][kk], bfr[n][kk], acc[m][n], 0,0,0);
    __syncthreads();
  }

  if (MODE == 0) {
    #pragma unroll
    for (int n=0;n<4;n++){
      int col = n0 + wn*64 + n*16 + lr;
      bf16* dst; int c;
      if (col < D_) { dst = out0; c = col; } else { dst = out1; c = col - D_; }
      float bv = (col < D_) ? bias0[c] : bias1[c];
      #pragma unroll
      for (int m=0;m<4;m++){
        #pragma unroll
        for (int j=0;j<4;j++){
          size_t row = (size_t)m0 + wm*64 + m*16 + lg*4 + j;
          dst[row*D_ + c] = (bf16)(acc[m][n][j] + bv);
        }
      }
    }
  } else if (MODE == 1) {
    #pragma unroll
    for (int n=0;n<4;n++){
      int col = n0 + wn*64 + n*16 + lr;
      int h = col >> 6, dh = col & 63;
      float bv = bias0[col];
      #pragma unroll
      for (int m=0;m<4;m++){
        int row = m0 + wm*64 + m*16 + lg*4;
        int b = row >> 9, s = row & 511;
        bf16x4 pk;
        #pragma unroll
        for (int j=0;j<4;j++) pk[j] = (bf16)(acc[m][n][j] + bv);
        *(bf16x4*)&out0[((size_t)(b*H_ + h)*DH_ + dh)*S_ + s] = pk;
      }
    }
  } else {
    #pragma unroll
    for (int m=0;m<4;m++){
      #pragma unroll
      for (int j=0;j<4;j++){
        size_t row = (size_t)m0 + wm*64 + m*16 + lg*4 + j;
        #pragma unroll
        for (int n=0;n<4;n++){
          int col = n0 + wn*64 + n*16 + lr;
          size_t idx = row*D_ + col;
          outf[idx] = acc[m][n][j] + bias0[col] + (float)res[idx];
        }
      }
    }
  }
}

// ---------------- Flash attention: 128 q-rows/block, swapped MFMA -------------
// K: [b][s][h][dh]; VT: [b][h][dh][s]. Grid (4,16,32), 4 waves.
__global__ __launch_bounds__(256) void attn_fwd(
    const bf16* __restrict__ Q, const bf16* __restrict__ K,
    const bf16* __restrict__ VT, const int* __restrict__ mask,
    bf16* __restrict__ ctx)
{
  int flat = blockIdx.x + (blockIdx.y<<2) + (blockIdx.z<<6);   // 2048 wgs
  int work = (flat & 7)*256 + (flat >> 3);
  int qt = work & 3, h = (work>>2) & 15, b = work >> 6;
  int q0 = qt*128;
  int t = threadIdx.x, w = t>>6, l = t&63, lr = l&15, lg = (l>>4)&3;

  __shared__ bf16 Q_sh[8192];               // 128 q-rows fragment-packed, 16KB
  __shared__ bf16 K_s0[4096], K_s1[4096];
  __shared__ bf16 V_s0[4096], V_s1[4096];
  __shared__ float msk[512];

  const float SC = 0.125f * 1.44269504f;
  for (int i=t;i<512;i+=256) msk[i] = mask[b*S_+i] ? 0.f : -1.44269504e9f;

  size_t qbase  = ((size_t)(b*S_ + q0)*H_ + h)*DH_;
  size_t vtbase = (size_t)(b*H_ + h)*DH_*S_;

  #pragma unroll
  for (int i=0;i<4;i++){
    int c = i*256 + t;
    int clr=c&15, clg=(c>>4)&3, ckk=(c>>6)&1, q16=c>>7;
    async16(Q + qbase + (size_t)(q16*16+clr)*D_ + ckk*32 + clg*8, &Q_sh[c*8]);
  }
  {
    size_t kb = ((size_t)(b*S_)*H_ + h)*DH_;
    #pragma unroll
    for (int i=0;i<2;i++){
      int c = i*256 + t;
      int clr=c&15, clg=(c>>4)&3, ckk=(c>>6)&1, n16=c>>7;
      async16(K + kb + (size_t)(n16*16+clr)*D_ + ckk*32 + clg*8, &K_s0[c*8]);
      async16(VT + vtbase + (size_t)(n16*16+clr)*S_ + ckk*32 + clg*8, &V_s0[c*8]);
    }
  }
  __syncthreads();

  bf16x8 qa[2][2];
  #pragma unroll
  for (int s=0;s<2;s++)
    #pragma unroll
    for (int kk=0;kk<2;kk++)
      qa[s][kk] = *(const bf16x8*)&Q_sh[((((s*4+w)*2+kk)*4+lg)*16+lr)*8];

  f32x4 cacc[2][4];
  #pragma unroll
  for (int s=0;s<2;s++)
    #pragma unroll
    for (int n=0;n<4;n++) cacc[s][n] = (f32x4){0.f,0.f,0.f,0.f};
  float mrun[2] = {-3.0e38f, -3.0e38f};
  float lrun[2] = {0.f, 0.f};

  union UPA { unsigned u[4]; bf16x8 v; };
  UPA pa[2][2];

  for (int kt=0; kt<8; ++kt) {
    const bf16* Ks = (kt&1) ? K_s1 : K_s0;
    const bf16* Vs = (kt&1) ? V_s1 : V_s0;
    if (kt < 7) {
      bf16* Kd = (kt&1) ? K_s0 : K_s1;
      bf16* Vd = (kt&1) ? V_s0 : V_s1;
      size_t kb = ((size_t)(b*S_ + (kt+1)*64)*H_ + h)*DH_;
      size_t vb = vtbase + (kt+1)*64;
      #pragma unroll
      for (int i=0;i<2;i++){
        int c = i*256 + t;
        int clr=c&15, clg=(c>>4)&3, ckk=(c>>6)&1, n16=c>>7;
        async16(K + kb + (size_t)(n16*16+clr)*D_ + ckk*32 + clg*8, &Kd[c*8]);
        async16(VT + vb + (size_t)(n16*16+clr)*S_ + ckk*32 + clg*8, &Vd[c*8]);
      }
    }

    // K fragments read ONCE, feed both q-subtiles
    bf16x8 kf[4][2];
    #pragma unroll
    for (int n=0;n<4;n++)
      #pragma unroll
      for (int kk=0;kk<2;kk++)
        kf[n][kk] = *(const bf16x8*)&Ks[(((n*2+kk)*4+lg)*16+lr)*8];

    #pragma unroll
    for (int s=0;s<2;s++){
      // S^T = mfma(K, Q): lane holds S^T[key=n*16+lg*4+j][q=w(16)+lr]
      float p[4][4];
      #pragma unroll
      for (int n=0;n<4;n++){
        f32x4 sa = (f32x4){0.f,0.f,0.f,0.f};
        #pragma unroll
        for (int kk=0;kk<2;kk++)
          sa = __builtin_amdgcn_mfma_f32_16x16x32_bf16(kf[n][kk], qa[s][kk], sa, 0,0,0);
        float4 mk = *(const float4*)&msk[kt*64 + n*16 + lg*4];
        p[n][0] = sa[0]*SC + mk.x;
        p[n][1] = sa[1]*SC + mk.y;
        p[n][2] = sa[2]*SC + mk.z;
        p[n][3] = sa[3]*SC + mk.w;
      }

      // tile max for this lane's q-row
      float pm = fmaxf(fmaxf(p[0][0],p[0][1]),fmaxf(p[0][2],p[0][3]));
      #pragma unroll
      for (int n=1;n<4;n++)
        pm = fmaxf(pm, fmaxf(fmaxf(p[n][0],p[n][1]),fmaxf(p[n][2],p[n][3])));
      pm = fmaxf(pm, __shfl_xor(pm, 16, 64));
      pm = fmaxf(pm, __shfl_xor(pm, 32, 64));

      // T13 defer-max: rescale only if max grew past threshold
      if (__any((int)(pm - mrun[s] > 8.f))) {
        float mnew  = fmaxf(mrun[s], pm);
        float alpha = FEXP2(mrun[s] - mnew);
        mrun[s] = mnew;
        lrun[s] *= alpha;
        #pragma unroll
        for (int n=0;n<4;n++) cacc[s][n] *= alpha;
      }
      float ps = 0.f;
      #pragma unroll
      for (int n=0;n<4;n++)
        #pragma unroll
        for (int j=0;j<4;j++){ p[n][j] = FEXP2(p[n][j] - mrun[s]); ps += p[n][j]; }
      ps += __shfl_xor(ps, 16, 64);
      ps += __shfl_xor(ps, 32, 64);
      lrun[s] += ps;

      // pack P -> bf16 pairs
      unsigned pk[4][2];
      #pragma unroll
      for (int n=0;n<4;n++)
        #pragma unroll
        for (int i=0;i<2;i++){
          union { bf16x2 v; unsigned u; } u2;
          u2.v[0] = (bf16)p[n][2*i];
          u2.v[1] = (bf16)p[n][2*i+1];
          pk[n][i] = u2.u;
        }
      // redistribute to PV B-fragment
      int srcbase = (l&15) + ((l&16)<<1);
      #pragma unroll
      for (int w4=0; w4<4; ++w4){
        int src = srcbase + ((w4&2)<<3);
        unsigned lo0 = __shfl(pk[0][w4&1], src, 64);
        unsigned hi0 = __shfl(pk[1][w4&1], src, 64);
        unsigned lo1 = __shfl(pk[2][w4&1], src, 64);
        unsigned hi1 = __shfl(pk[3][w4&1], src, 64);
        pa[s][0].u[w4] = (l&32) ? hi0 : lo0;
        pa[s][1].u[w4] = (l&32) ? hi1 : lo1;
      }
    }

    // PV: V fragments read ONCE, feed both q-subtiles
    #pragma unroll
    for (int nd=0;nd<4;nd++){
      bf16x8 vb0 = *(const bf16x8*)&Vs[(((nd*2+0)*4+lg)*16+lr)*8];
      bf16x8 vb1 = *(const bf16x8*)&Vs[(((nd*2+1)*4+lg)*16+lr)*8];
      #pragma unroll
      for (int s=0;s<2;s++){
        cacc[s][nd] = __builtin_amdgcn_mfma_f32_16x16x32_bf16(vb0, pa[s][0].v, cacc[s][nd], 0,0,0);
        cacc[s][nd] = __builtin_amdgcn_mfma_f32_16x16x32_bf16(vb1, pa[s][1].v, cacc[s][nd], 0,0,0);
      }
    }
    __syncthreads();
  }

  #pragma unroll
  for (int s=0;s<2;s++){
    float rl = 1.0f / lrun[s];
    size_t obase = qbase + (size_t)(s*64 + w*16 + lr)*D_;
    #pragma unroll
    for (int nd=0;nd<4;nd++){
      bf16x4 o4;
      #pragma unroll
      for (int j=0;j<4;j++) o4[j] = (bf16)(cacc[s][nd][j]*rl);
      *(bf16x4*)&ctx[obase + nd*16 + lg*4] = o4;
    }
  }
}

// ------------------------------ launcher --------------------------------------
extern "C" void kernel_launch(void* const* d_in, const int* in_sizes, int n_in,
                              void* d_out, int out_size, void* d_ws, size_t ws_size,
                              hipStream_t stream)
{
  (void)in_sizes; (void)n_in; (void)out_size; (void)ws_size;
  const float* qk   = (const float*)d_in[0];
  const float* v    = (const float*)d_in[1];
  const int*   mask = (const int*)  d_in[2];
  const float* qk_g = (const float*)d_in[3];
  const float* qk_b = (const float*)d_in[4];
  const float* v_g  = (const float*)d_in[5];
  const float* v_b  = (const float*)d_in[6];
  const float* Wq   = (const float*)d_in[7];
  const float* bq   = (const float*)d_in[8];
  const float* Wk   = (const float*)d_in[9];
  const float* bk   = (const float*)d_in[10];
  const float* Wv   = (const float*)d_in[11];
  const float* bv   = (const float*)d_in[12];
  const float* Wo   = (const float*)d_in[13];
  const float* bo   = (const float*)d_in[14];
  float* out = (float*)d_out;

  char* ws = (char*)d_ws;
  size_t off = 0;
  auto alloc = [&](size_t bytes){ void* p = ws + off; off += (bytes + 255) & ~(size_t)255; return p; };
  bf16* qkn  = (bf16*)alloc((size_t)M_*D_*2);
  bf16* vn   = (bf16*)alloc((size_t)M_*D_*2);
  bf16* Qb   = (bf16*)alloc((size_t)M_*D_*2);
  bf16* Kb   = (bf16*)alloc((size_t)M_*D_*2);
  bf16* VTb  = (bf16*)alloc((size_t)M_*D_*2);
  bf16* Cb   = (bf16*)alloc((size_t)M_*D_*2);
  bf16* WqkT = (bf16*)alloc((size_t)2*D_*D_*2);
  bf16* WvT  = (bf16*)alloc((size_t)D_*D_*2);
  bf16* WoT  = (bf16*)alloc((size_t)D_*D_*2);

  ln_bf16<<<2*M_, 256, 0, stream>>>(qk, v, qk_g, qk_b, v_g, v_b, qkn, vn);
  wtrans<<<dim3(32,32,4), dim3(32,8), 0, stream>>>(Wq, Wk, Wv, Wo,
      WqkT, WqkT + (size_t)D_*D_, WvT, WoT);
  gemm_bt<0><<<dim3(16,128), 256, 0, stream>>>(qkn, WqkT, bq, bk, nullptr, Qb, Kb, nullptr);
  gemm_bt<1><<<dim3(8,128),  256, 0, stream>>>(vn,  WvT,  bv, nullptr, nullptr, VTb, nullptr, nullptr);
  attn_fwd<<<dim3(4, 16, 32), 256, 0, stream>>>(Qb, Kb, VTb, mask, Cb);
  gemm_bt<2><<<dim3(8,128),  256, 0, stream>>>(Cb, WoT, bo, nullptr, vn, nullptr, nullptr, out);
}

// Round 5
// 279.659 us; speedup vs baseline: 1.5334x; 1.0640x over previous
//
#include <hip/hip_runtime.h>
#include <hip/hip_bf16.h>

typedef __bf16 bf16;
typedef __bf16 bf16x2 __attribute__((ext_vector_type(2)));
typedef __bf16 bf16x4 __attribute__((ext_vector_type(4)));
typedef __bf16 bf16x8 __attribute__((ext_vector_type(8)));
typedef float f32x4 __attribute__((ext_vector_type(4)));

#define B_ 32
#define S_ 512
#define D_ 1024
#define H_ 16
#define DH_ 64
#define M_ (B_*S_)   // 16384

#if __has_builtin(__builtin_amdgcn_exp2f)
#define FEXP2 __builtin_amdgcn_exp2f
#else
#define FEXP2 exp2f
#endif

__device__ __forceinline__ void async16(const void* g, void* l) {
  __builtin_amdgcn_global_load_lds(
      (const __attribute__((address_space(1))) unsigned int*)g,
      (__attribute__((address_space(3))) unsigned int*)l, 16, 0, 0);
}

// ---------------- LayerNorm + bf16 cast (both tensors in one launch) ----------
__global__ __launch_bounds__(256) void ln_bf16(
    const float* __restrict__ qk, const float* __restrict__ v,
    const float* __restrict__ g1, const float* __restrict__ b1,
    const float* __restrict__ g2, const float* __restrict__ b2,
    bf16* __restrict__ o1, bf16* __restrict__ o2)
{
  int row = blockIdx.x;
  const float* src; const float* g; const float* b; bf16* o; int r;
  if (row < M_) { src=qk; g=g1; b=b1; o=o1; r=row; }
  else          { src=v;  g=g2; b=b2; o=o2; r=row-M_; }
  int t = threadIdx.x;
  float4 x = ((const float4*)(src + (size_t)r*D_))[t];
  float s  = x.x+x.y+x.z+x.w;
  float ss = x.x*x.x + x.y*x.y + x.z*x.z + x.w*x.w;
  #pragma unroll
  for (int off=32; off>=1; off>>=1) {
    s  += __shfl_xor(s,  off, 64);
    ss += __shfl_xor(ss, off, 64);
  }
  __shared__ float red[8];
  int w = t>>6, l = t&63;
  if (l==0){ red[w]=s; red[4+w]=ss; }
  __syncthreads();
  s  = red[0]+red[1]+red[2]+red[3];
  ss = red[4]+red[5]+red[6]+red[7];
  float mu  = s*(1.f/D_);
  float var = ss*(1.f/D_) - mu*mu;
  float rs  = rsqrtf(var + 1e-5f);
  float4 gg = ((const float4*)g)[t];
  float4 bb = ((const float4*)b)[t];
  bf16x4 ov;
  ov[0] = (bf16)((x.x-mu)*rs*gg.x + bb.x);
  ov[1] = (bf16)((x.y-mu)*rs*gg.y + bb.y);
  ov[2] = (bf16)((x.z-mu)*rs*gg.z + bb.z);
  ov[3] = (bf16)((x.w-mu)*rs*gg.w + bb.w);
  ((bf16x4*)(o + (size_t)r*D_))[t] = ov;
}

// ---------------- Weight transpose + bf16 cast: Wt[N][K] = W[K][N] ------------
__global__ void wtrans(const float* __restrict__ W0, const float* __restrict__ W1,
                       const float* __restrict__ W2, const float* __restrict__ W3,
                       bf16* __restrict__ o0, bf16* __restrict__ o1,
                       bf16* __restrict__ o2, bf16* __restrict__ o3)
{
  int z = blockIdx.z;
  const float* W = z==0?W0: z==1?W1: z==2?W2: W3;
  bf16* o        = z==0?o0: z==1?o1: z==2?o2: o3;
  __shared__ float tile[32][33];
  int n0 = blockIdx.x*32, k0 = blockIdx.y*32;
  int tx = threadIdx.x, ty = threadIdx.y;   // block (32,8)
  #pragma unroll
  for (int i=0;i<4;i++) tile[ty + i*8][tx] = W[(size_t)(k0+ty+i*8)*D_ + n0+tx];
  __syncthreads();
  #pragma unroll
  for (int i=0;i<4;i++) o[(size_t)(n0+ty+i*8)*D_ + k0+tx] = (bf16)tile[tx][ty+i*8];
}

// ---------------- GEMM: C[M,N] = A[M,K] * Bt[N,K]^T + bias -------------------
// 128x128 tile, BK=64, dbuf LDS, depth-2 prefetch, counted vmcnt (T3+T4), T5.
template<int MODE>
__global__ __launch_bounds__(256) void gemm_bt(
    const bf16* __restrict__ A, const bf16* __restrict__ Bt,
    const float* __restrict__ bias0, const float* __restrict__ bias1,
    const bf16* __restrict__ res,
    bf16* __restrict__ out0, bf16* __restrict__ out1, float* __restrict__ outf)
{
  __shared__ bf16 A_sh[2][128*64];
  __shared__ bf16 B_sh[2][128*64];
  int t = threadIdx.x;
  int nwg  = gridDim.x * gridDim.y;
  int orig = blockIdx.y * gridDim.x + blockIdx.x;
  int qch  = nwg >> 3;
  int wg   = (orig & 7) * qch + (orig >> 3);
  int bx = wg % gridDim.x, by = wg / gridDim.x;
  int n0 = bx*128, m0 = by*128;
  int w = t>>6, l = t&63, lr = l&15, lg = (l>>4)&3;
  int wm = w>>1, wn = w&1;

  auto stage = [&](int buf, int kt){
    const bf16* Ab = A  + (size_t)m0*D_ + kt*64;
    const bf16* Bb = Bt + (size_t)n0*D_ + kt*64;
    #pragma unroll
    for (int i=0;i<4;i++){
      int c = i*256 + t;
      int row = c>>3, slot = (c&7) ^ (row&7);
      async16(Ab + (size_t)row*D_ + slot*8, &A_sh[buf][c*8]);
      async16(Bb + (size_t)row*D_ + slot*8, &B_sh[buf][c*8]);
    }
  };

  f32x4 acc[4][4];
  #pragma unroll
  for (int m=0;m<4;m++)
    #pragma unroll
    for (int n=0;n<4;n++) acc[m][n] = (f32x4){0.f,0.f,0.f,0.f};

  stage(0, 0);
  stage(1, 1);
  asm volatile("s_waitcnt vmcnt(8)" ::: "memory");   // tile 0 landed, tile 1 in flight
  __builtin_amdgcn_s_barrier();

  for (int kt=0; kt<16; ++kt) {
    int cur = kt & 1;
    // register fragments from the buffer about to be recycled
    bf16x8 af[4][2], bfr[4][2];
    #pragma unroll
    for (int m=0;m<4;m++){
      int row = wm*64 + m*16 + lr;
      #pragma unroll
      for (int kk=0;kk<2;kk++)
        af[m][kk] = *(const bf16x8*)&A_sh[cur][row*64 + (((kk*4+lg)^(lr&7))*8)];
    }
    #pragma unroll
    for (int n=0;n<4;n++){
      int row = wn*64 + n*16 + lr;
      #pragma unroll
      for (int kk=0;kk<2;kk++)
        bfr[n][kk] = *(const bf16x8*)&B_sh[cur][row*64 + (((kk*4+lg)^(lr&7))*8)];
    }
    asm volatile("s_waitcnt lgkmcnt(0)" ::: "memory"); // my reads complete
    __builtin_amdgcn_sched_barrier(0);
    __builtin_amdgcn_s_barrier();                      // all waves' reads complete
    if (kt+2 < 16) stage(cur, kt+2);                   // recycle buffer
    __builtin_amdgcn_s_setprio(1);
    #pragma unroll
    for (int kk=0;kk<2;kk++)
      #pragma unroll
      for (int m=0;m<4;m++)
        #pragma unroll
        for (int n=0;n<4;n++)
          acc[m][n] = __builtin_amdgcn_mfma_f32_16x16x32_bf16(af[m][kk], bfr[n][kk], acc[m][n], 0,0,0);
    __builtin_amdgcn_s_setprio(0);
    if (kt < 14)       asm volatile("s_waitcnt vmcnt(8)" ::: "memory"); // next tile landed, one in flight
    else if (kt == 14) asm volatile("s_waitcnt vmcnt(0)" ::: "memory"); // last tile
    if (kt < 15) { __builtin_amdgcn_sched_barrier(0); __builtin_amdgcn_s_barrier(); }
  }

  if (MODE == 0) {
    #pragma unroll
    for (int n=0;n<4;n++){
      int col = n0 + wn*64 + n*16 + lr;
      bf16* dst; int c;
      if (col < D_) { dst = out0; c = col; } else { dst = out1; c = col - D_; }
      float bv = (col < D_) ? bias0[c] : bias1[c];
      #pragma unroll
      for (int m=0;m<4;m++){
        #pragma unroll
        for (int j=0;j<4;j++){
          size_t row = (size_t)m0 + wm*64 + m*16 + lg*4 + j;
          dst[row*D_ + c] = (bf16)(acc[m][n][j] + bv);
        }
      }
    }
  } else if (MODE == 1) {
    #pragma unroll
    for (int n=0;n<4;n++){
      int col = n0 + wn*64 + n*16 + lr;
      int h = col >> 6, dh = col & 63;
      float bv = bias0[col];
      #pragma unroll
      for (int m=0;m<4;m++){
        int row = m0 + wm*64 + m*16 + lg*4;
        int b = row >> 9, s = row & 511;
        bf16x4 pk;
        #pragma unroll
        for (int j=0;j<4;j++) pk[j] = (bf16)(acc[m][n][j] + bv);
        *(bf16x4*)&out0[((size_t)(b*H_ + h)*DH_ + dh)*S_ + s] = pk;
      }
    }
  } else {
    #pragma unroll
    for (int m=0;m<4;m++){
      #pragma unroll
      for (int j=0;j<4;j++){
        size_t row = (size_t)m0 + wm*64 + m*16 + lg*4 + j;
        #pragma unroll
        for (int n=0;n<4;n++){
          int col = n0 + wn*64 + n*16 + lr;
          size_t idx = row*D_ + col;
          outf[idx] = acc[m][n][j] + bias0[col] + (float)res[idx];
        }
      }
    }
  }
}

// ---------------- Flash attention: 128 q-rows/block, ring-3 KV, counted vmcnt -
// K: [b][s][h][dh]; VT: [b][h][dh][s]. Grid (4,16,32), 4 waves.
__global__ __launch_bounds__(256) void attn_fwd(
    const bf16* __restrict__ Q, const bf16* __restrict__ K,
    const bf16* __restrict__ VT, const int* __restrict__ mask,
    bf16* __restrict__ ctx)
{
  int flat = blockIdx.x + (blockIdx.y<<2) + (blockIdx.z<<6);   // 2048 wgs
  int work = (flat & 7)*256 + (flat >> 3);
  int qt = work & 3, h = (work>>2) & 15, b = work >> 6;
  int q0 = qt*128;
  int t = threadIdx.x, w = t>>6, l = t&63, lr = l&15, lg = (l>>4)&3;

  __shared__ bf16 K_s[3][4096];
  __shared__ bf16 V_s[3][4096];
  __shared__ float msk[512];

  const float SC = 0.125f * 1.44269504f;
  for (int i=t;i<512;i+=256) msk[i] = mask[b*S_+i] ? 0.f : -1.44269504e9f;

  size_t qbase  = ((size_t)(b*S_ + q0)*H_ + h)*DH_;
  size_t vtbase = (size_t)(b*H_ + h)*DH_*S_;

  auto stageKV = [&](int slot, int kt){
    size_t kb = ((size_t)(b*S_ + kt*64)*H_ + h)*DH_;
    size_t vb = vtbase + kt*64;
    #pragma unroll
    for (int i=0;i<2;i++){
      int c = i*256 + t;
      int clr=c&15, clg=(c>>4)&3, ckk=(c>>6)&1, n16=c>>7;
      async16(K + kb + (size_t)(n16*16+clr)*D_ + ckk*32 + clg*8, &K_s[slot][c*8]);
      async16(VT + vb + (size_t)(n16*16+clr)*S_ + ckk*32 + clg*8, &V_s[slot][c*8]);
    }
  };

  // Q straight to registers (per-lane 16B loads)
  bf16x8 qa[2][2];
  #pragma unroll
  for (int s=0;s<2;s++)
    #pragma unroll
    for (int kk=0;kk<2;kk++)
      qa[s][kk] = *(const bf16x8*)(Q + qbase + (size_t)(s*64 + w*16 + lr)*D_ + kk*32 + lg*8);

  stageKV(0, 0);
  stageKV(1, 1);
  asm volatile("s_waitcnt vmcnt(4) lgkmcnt(0)" ::: "memory"); // tile0 + msk ready
  __builtin_amdgcn_s_barrier();

  f32x4 cacc[2][4];
  #pragma unroll
  for (int s=0;s<2;s++)
    #pragma unroll
    for (int n=0;n<4;n++) cacc[s][n] = (f32x4){0.f,0.f,0.f,0.f};
  float mrun[2] = {-3.0e38f, -3.0e38f};
  float lrun[2] = {0.f, 0.f};

  union UPA { unsigned u[4]; bf16x8 v; };
  UPA pa[2][2];

  for (int kt=0; kt<8; ++kt) {
    const bf16* Ks = K_s[kt%3];
    const bf16* Vs = V_s[kt%3];
    if (kt+2 < 8) stageKV((kt+2)%3, kt+2);   // slot was consumed at iter kt-1

    // K fragments read ONCE, feed both q-subtiles
    bf16x8 kf[4][2];
    #pragma unroll
    for (int n=0;n<4;n++)
      #pragma unroll
      for (int kk=0;kk<2;kk++)
        kf[n][kk] = *(const bf16x8*)&Ks[(((n*2+kk)*4+lg)*16+lr)*8];

    #pragma unroll
    for (int s=0;s<2;s++){
      float p[4][4];
      #pragma unroll
      for (int n=0;n<4;n++){
        f32x4 sa = (f32x4){0.f,0.f,0.f,0.f};
        #pragma unroll
        for (int kk=0;kk<2;kk++)
          sa = __builtin_amdgcn_mfma_f32_16x16x32_bf16(kf[n][kk], qa[s][kk], sa, 0,0,0);
        float4 mk = *(const float4*)&msk[kt*64 + n*16 + lg*4];
        p[n][0] = sa[0]*SC + mk.x;
        p[n][1] = sa[1]*SC + mk.y;
        p[n][2] = sa[2]*SC + mk.z;
        p[n][3] = sa[3]*SC + mk.w;
      }

      float pm = fmaxf(fmaxf(p[0][0],p[0][1]),fmaxf(p[0][2],p[0][3]));
      #pragma unroll
      for (int n=1;n<4;n++)
        pm = fmaxf(pm, fmaxf(fmaxf(p[n][0],p[n][1]),fmaxf(p[n][2],p[n][3])));
      pm = fmaxf(pm, __shfl_xor(pm, 16, 64));
      pm = fmaxf(pm, __shfl_xor(pm, 32, 64));

      if (__any((int)(pm - mrun[s] > 8.f))) {
        float mnew  = fmaxf(mrun[s], pm);
        float alpha = FEXP2(mrun[s] - mnew);
        mrun[s] = mnew;
        lrun[s] *= alpha;
        #pragma unroll
        for (int n=0;n<4;n++) cacc[s][n] *= alpha;
      }
      float ps = 0.f;
      #pragma unroll
      for (int n=0;n<4;n++)
        #pragma unroll
        for (int j=0;j<4;j++){ p[n][j] = FEXP2(p[n][j] - mrun[s]); ps += p[n][j]; }
      ps += __shfl_xor(ps, 16, 64);
      ps += __shfl_xor(ps, 32, 64);
      lrun[s] += ps;

      unsigned pk[4][2];
      #pragma unroll
      for (int n=0;n<4;n++)
        #pragma unroll
        for (int i=0;i<2;i++){
          union { bf16x2 v; unsigned u; } u2;
          u2.v[0] = (bf16)p[n][2*i];
          u2.v[1] = (bf16)p[n][2*i+1];
          pk[n][i] = u2.u;
        }
      int srcbase = (l&15) + ((l&16)<<1);
      #pragma unroll
      for (int w4=0; w4<4; ++w4){
        int src = srcbase + ((w4&2)<<3);
        unsigned lo0 = __shfl(pk[0][w4&1], src, 64);
        unsigned hi0 = __shfl(pk[1][w4&1], src, 64);
        unsigned lo1 = __shfl(pk[2][w4&1], src, 64);
        unsigned hi1 = __shfl(pk[3][w4&1], src, 64);
        pa[s][0].u[w4] = (l&32) ? hi0 : lo0;
        pa[s][1].u[w4] = (l&32) ? hi1 : lo1;
      }
    }

    #pragma unroll
    for (int nd=0;nd<4;nd++){
      bf16x8 vb0 = *(const bf16x8*)&Vs[(((nd*2+0)*4+lg)*16+lr)*8];
      bf16x8 vb1 = *(const bf16x8*)&Vs[(((nd*2+1)*4+lg)*16+lr)*8];
      #pragma unroll
      for (int s=0;s<2;s++){
        cacc[s][nd] = __builtin_amdgcn_mfma_f32_16x16x32_bf16(vb0, pa[s][0].v, cacc[s][nd], 0,0,0);
        cacc[s][nd] = __builtin_amdgcn_mfma_f32_16x16x32_bf16(vb1, pa[s][1].v, cacc[s][nd], 0,0,0);
      }
    }

    asm volatile("s_waitcnt lgkmcnt(0)" ::: "memory");      // my LDS reads done
    if (kt < 6)       asm volatile("s_waitcnt vmcnt(4)" ::: "memory");  // tile kt+1 landed
    else if (kt == 6) asm volatile("s_waitcnt vmcnt(0)" ::: "memory");
    if (kt < 7) { __builtin_amdgcn_sched_barrier(0); __builtin_amdgcn_s_barrier(); }
  }

  #pragma unroll
  for (int s=0;s<2;s++){
    float rl = 1.0f / lrun[s];
    size_t obase = qbase + (size_t)(s*64 + w*16 + lr)*D_;
    #pragma unroll
    for (int nd=0;nd<4;nd++){
      bf16x4 o4;
      #pragma unroll
      for (int j=0;j<4;j++) o4[j] = (bf16)(cacc[s][nd][j]*rl);
      *(bf16x4*)&ctx[obase + nd*16 + lg*4] = o4;
    }
  }
}

// ------------------------------ launcher --------------------------------------
extern "C" void kernel_launch(void* const* d_in, const int* in_sizes, int n_in,
                              void* d_out, int out_size, void* d_ws, size_t ws_size,
                              hipStream_t stream)
{
  (void)in_sizes; (void)n_in; (void)out_size; (void)ws_size;
  const float* qk   = (const float*)d_in[0];
  const float* v    = (const float*)d_in[1];
  const int*   mask = (const int*)  d_in[2];
  const float* qk_g = (const float*)d_in[3];
  const float* qk_b = (const float*)d_in[4];
  const float* v_g  = (const float*)d_in[5];
  const float* v_b  = (const float*)d_in[6];
  const float* Wq   = (const float*)d_in[7];
  const float* bq   = (const float*)d_in[8];
  const float* Wk   = (const float*)d_in[9];
  const float* bk   = (const float*)d_in[10];
  const float* Wv   = (const float*)d_in[11];
  const float* bv   = (const float*)d_in[12];
  const float* Wo   = (const float*)d_in[13];
  const float* bo   = (const float*)d_in[14];
  float* out = (float*)d_out;

  char* ws = (char*)d_ws;
  size_t off = 0;
  auto alloc = [&](size_t bytes){ void* p = ws + off; off += (bytes + 255) & ~(size_t)255; return p; };
  bf16* qkn  = (bf16*)alloc((size_t)M_*D_*2);
  bf16* vn   = (bf16*)alloc((size_t)M_*D_*2);
  bf16* Qb   = (bf16*)alloc((size_t)M_*D_*2);
  bf16* Kb   = (bf16*)alloc((size_t)M_*D_*2);
  bf16* VTb  = (bf16*)alloc((size_t)M_*D_*2);
  bf16* Cb   = (bf16*)alloc((size_t)M_*D_*2);
  bf16* WqkT = (bf16*)alloc((size_t)2*D_*D_*2);
  bf16* WvT  = (bf16*)alloc((size_t)D_*D_*2);
  bf16* WoT  = (bf16*)alloc((size_t)D_*D_*2);

  ln_bf16<<<2*M_, 256, 0, stream>>>(qk, v, qk_g, qk_b, v_g, v_b, qkn, vn);
  wtrans<<<dim3(32,32,4), dim3(32,8), 0, stream>>>(Wq, Wk, Wv, Wo,
      WqkT, WqkT + (size_t)D_*D_, WvT, WoT);
  gemm_bt<0><<<dim3(16,128), 256, 0, stream>>>(qkn, WqkT, bq, bk, nullptr, Qb, Kb, nullptr);
  gemm_bt<1><<<dim3(8,128),  256, 0, stream>>>(vn,  WvT,  bv, nullptr, nullptr, VTb, nullptr, nullptr);
  attn_fwd<<<dim3(4, 16, 32), 256, 0, stream>>>(Qb, Kb, VTb, mask, Cb);
  gemm_bt<2><<<dim3(8,128),  256, 0, stream>>>(Cb, WoT, bo, nullptr, vn, nullptr, nullptr, out);
}